// Round 5
// baseline (6791.806 us; speedup 1.0000x reference)
//
#include <hip/hip_runtime.h>
#include <math.h>

// Problem constants
#define DD   512
#define LSEQ 2048
#define NBAT 16
#define RTOT (NBAT * LSEQ)   // 32768 rows
#define WREC 8               // workgroups in recurrence
#define RING 64              // h ring depth (1 MB; defeats consumer-L1 staleness)

typedef __attribute__((ext_vector_type(8))) short bf16x8;
typedef __attribute__((ext_vector_type(4))) float f32x4;

#define AS1(p) ((const __attribute__((address_space(1))) void*)(p))
#define AS3(p) ((__attribute__((address_space(3))) void*)(p))
#define MFMA16 __builtin_amdgcn_mfma_f32_16x16x32_bf16

__device__ __forceinline__ unsigned short f2bf(float f) {
  unsigned u = __builtin_bit_cast(unsigned, f);
  u += 0x7fffu + ((u >> 16) & 1u);
  return (unsigned short)(u >> 16);
}

// ---------------------------------------------------------------------------
// prep: fold BN into Wx (Wx' = Wx*diag(inv), b' = Wx(beta-mean*inv)+b_rnn),
// convert Wffn to bf16.  blocks 0..511: Wx' row + b' ; blocks 512..1535: Wffn.
// ---------------------------------------------------------------------------
__global__ __launch_bounds__(256) void prep_kernel(
    const float* __restrict__ Wx, const float* __restrict__ gamma,
    const float* __restrict__ beta, const float* __restrict__ mean,
    const float* __restrict__ var, const float* __restrict__ brnn,
    const float* __restrict__ Wffn,
    unsigned short* __restrict__ Wxp, unsigned short* __restrict__ Wfb,
    float* __restrict__ bprime)
{
  const unsigned tid = threadIdx.x, bx = blockIdx.x;
  if (bx < 512) {
    __shared__ float red[256];
    float partial = 0.f;
#pragma unroll
    for (int i = 0; i < 2; ++i) {
      unsigned d = i * 256u + tid;
      float iv = gamma[d] * rsqrtf(var[d] + 1e-5f);
      float w  = Wx[bx * 512u + d];
      Wxp[bx * 512u + d] = (unsigned short)f2bf(w * iv);
      partial += w * (beta[d] - mean[d] * iv);
    }
    red[tid] = partial; __syncthreads();
    for (unsigned s = 128; s > 0; s >>= 1) {
      if (tid < s) red[tid] += red[tid + s];
      __syncthreads();
    }
    if (tid == 0) bprime[bx] = red[0] + brnn[bx];
  } else {
    unsigned row = bx - 512;
#pragma unroll
    for (int i = 0; i < 2; ++i) {
      unsigned d = i * 256u + tid;
      Wfb[row * 512u + d] = (unsigned short)f2bf(Wffn[row * 512u + d]);
    }
  }
}

// ---------------------------------------------------------------------------
// convert x (fp32) -> bf16, row-major (RTOT, D)
// ---------------------------------------------------------------------------
__global__ __launch_bounds__(256) void convx_kernel(
    const float* __restrict__ x, unsigned short* __restrict__ Xbf)
{
  const unsigned total4 = RTOT * DD / 4;
  unsigned i = blockIdx.x * 256u + threadIdx.x;
  const unsigned stride = gridDim.x * 256u;
  const float4* __restrict__ x4 = (const float4*)x;
  for (; i < total4; i += stride) {
    float4 v = x4[i];
    unsigned short o0 = f2bf(v.x), o1 = f2bf(v.y), o2 = f2bf(v.z), o3 = f2bf(v.w);
    unsigned long long pack = (unsigned long long)o0 |
                              ((unsigned long long)o1 << 16) |
                              ((unsigned long long)o2 << 32) |
                              ((unsigned long long)o3 << 48);
    *(unsigned long long*)(Xbf + i * 4u) = pack;
  }
}

// ---------------------------------------------------------------------------
// GEMM1: U[r,e] = sum_d Xbf[r,d]*Wxp[e,d] + b'[e]   (fp32 out into d_out)
// ---------------------------------------------------------------------------
__global__ __launch_bounds__(256) void gemm_u_kernel(
    const unsigned short* __restrict__ A, const unsigned short* __restrict__ Bw,
    const float* __restrict__ bias, float* __restrict__ U)
{
  __shared__ __align__(16) unsigned char lds[16384]; // A 8KB | B 8KB
  const unsigned tid = threadIdx.x;
  const unsigned lid = tid & 63u, wid = tid >> 6;
  const unsigned wr = wid >> 1, wc = wid & 1u;
  const unsigned rbase = blockIdx.x * 128u, nbase = blockIdx.y * 128u;

  f32x4 acc[4][4] = {};
  for (int kt = 0; kt < 16; ++kt) {
    __syncthreads();
#pragma unroll
    for (int i = 0; i < 2; ++i) {
      unsigned c = i * 256u + tid;
      const unsigned short* g = A + (rbase + (c >> 2)) * 512u + kt * 32u + (c & 3u) * 8u;
      __builtin_amdgcn_global_load_lds(AS1(g), AS3(lds + c * 16u), 16, 0, 0);
    }
#pragma unroll
    for (int i = 0; i < 2; ++i) {
      unsigned c = i * 256u + tid;
      const unsigned short* g = Bw + (nbase + (c >> 2)) * 512u + kt * 32u + (c & 3u) * 8u;
      __builtin_amdgcn_global_load_lds(AS1(g), AS3(lds + 8192u + c * 16u), 16, 0, 0);
    }
    __syncthreads();
    bf16x8 af[4], bfr[4];
#pragma unroll
    for (int mi = 0; mi < 4; ++mi)
      af[mi] = *(const bf16x8*)(lds + (wr * 64u + mi * 16u + (lid & 15u)) * 64u + (lid >> 4) * 16u);
#pragma unroll
    for (int ni = 0; ni < 4; ++ni)
      bfr[ni] = *(const bf16x8*)(lds + 8192u + (wc * 64u + ni * 16u + (lid & 15u)) * 64u + (lid >> 4) * 16u);
#pragma unroll
    for (int mi = 0; mi < 4; ++mi)
#pragma unroll
      for (int ni = 0; ni < 4; ++ni)
        acc[mi][ni] = MFMA16(af[mi], bfr[ni], acc[mi][ni], 0, 0, 0);
  }
#pragma unroll
  for (int mi = 0; mi < 4; ++mi)
#pragma unroll
    for (int ni = 0; ni < 4; ++ni) {
      unsigned e = nbase + wc * 64u + ni * 16u + (lid & 15u);
      float bb = bias[e];
#pragma unroll
      for (int j = 0; j < 4; ++j) {
        unsigned r = rbase + wr * 64u + mi * 16u + (lid >> 4) * 4u + j;
        U[r * 512u + e] = acc[mi][ni][j] + bb;
      }
    }
}

// ---------------------------------------------------------------------------
// Recurrence, single-XCD, per-WAVE flags, no intra-WG barrier:
//   - 256 blocks; XCC_ID claim; first XCD to 8 claimants wins (CAS), rest exit.
//   - 32 waves total; wave (g*4+w) owns flag line ctrl[(g*4+w)*16] (64B apart).
//   - poll: lanes 0-31 atomic-LOAD (RELAXED/AGENT, L1-bypassing, no RMW
//     serialization) the 32 flag lines; ballot until all >= st-1.
//   - release: ring-stores -> Hs-stores -> s_waitcnt vmcnt(4) (ring ack'd in
//     XCD L2) -> lane0 relaxed atomic store to own flag -> U prefetch.
//   - h exchange: plain stores/loads on 64-slot ring in XCD-shared L2
//     (write-through L1; reuse distance 1MB >> 32KB L1 => never stale).
//   - max inter-wave skew = 1 step by poll construction.
// ---------------------------------------------------------------------------
__global__ __launch_bounds__(256) void rnn_rec_kernel(
    const float* __restrict__ Wh, const float* __restrict__ U,
    unsigned short* __restrict__ Hs, unsigned short* __restrict__ ring,
    unsigned int* __restrict__ ctrl)
{
  __shared__ unsigned s_g;
  if (threadIdx.x == 0) {
    unsigned xcc;
    asm volatile("s_getreg_b32 %0, hwreg(HW_REG_XCC_ID)" : "=s"(xcc));
    xcc &= 7u;
    unsigned mygrp = 0xffffffffu;
    unsigned slot = __hip_atomic_fetch_add(&ctrl[512 + xcc], 1u, __ATOMIC_RELAXED,
                                           __HIP_MEMORY_SCOPE_AGENT);
    if (slot < 8u) {
      if (slot == 7u) {
        unsigned expected = 0u;
        __hip_atomic_compare_exchange_strong(&ctrl[520], &expected, xcc + 1u,
            __ATOMIC_RELEASE, __ATOMIC_RELAXED, __HIP_MEMORY_SCOPE_AGENT);
      }
      unsigned ch, gu = 0;
      do {
        ch = __hip_atomic_load(&ctrl[520], __ATOMIC_ACQUIRE, __HIP_MEMORY_SCOPE_AGENT);
      } while (ch == 0u && ++gu < 200000000u);
      if (ch == xcc + 1u) mygrp = slot;
    }
    s_g = mygrp;
  }
  __syncthreads();
  const unsigned g = s_g;
  if (g == 0xffffffffu) return;

  const unsigned tid = threadIdx.x, lid = tid & 63u, w = tid >> 6;
  const unsigned col = g * 64u + w * 16u + (lid & 15u);
  const unsigned kb = (lid >> 4) * 8u;
  const unsigned wflag = (g * 4u + w) * 16u;

  // stationary B fragments: B[k][n] = Wh[n][k]
  bf16x8 bfrag[16];
#pragma unroll
  for (int kc = 0; kc < 16; ++kc) {
    bf16x8 tf;
#pragma unroll
    for (int j = 0; j < 8; ++j)
      tf[j] = (short)f2bf(Wh[col * 512u + kc * 32u + kb + j]);
    bfrag[kc] = tf;
  }

  // prefetch u for step 1 (t index 0)
  float uv[4];
#pragma unroll
  for (int j = 0; j < 4; ++j) {
    unsigned m = (lid >> 4) * 4u + j;
    uv[j] = U[(m * (unsigned)LSEQ + 0u) * 512u + col];
  }

  unsigned spin_budget = 50000000u;  // cumulative valve: deadlock -> fast wrong
                                     // answer, never a 600s timeout
  for (unsigned st = 1; st <= LSEQ; ++st) {
    const unsigned tgt = st - 1;
    // all waves poll: lanes 0-31 each atomic-load one flag line, ballot
    while (true) {
      unsigned f = 0xffffffffu;
      if (lid < 32u)
        f = __hip_atomic_load(&ctrl[lid * 16u], __ATOMIC_RELAXED,
                              __HIP_MEMORY_SCOPE_AGENT);
      if (__ballot(f >= tgt) == ~0ull) break;
      if (--spin_budget == 0u) break;
    }

    // load h_{t-1} from the ring (plain loads; same-XCD L2; L1 cold by ring)
    const unsigned short* hb = ring + ((st - 1u) & (RING - 1u)) * 8192u;
    bf16x8 af[16];
#pragma unroll
    for (int kc = 0; kc < 16; ++kc)
      af[kc] = *(const bf16x8*)(hb + (lid & 15u) * 512u + kc * 32u + kb);

    f32x4 a0 = {}, a1 = {}, a2 = {}, a3 = {};
#pragma unroll
    for (int kc = 0; kc < 4; ++kc)  a0 = MFMA16(af[kc],      bfrag[kc],      a0, 0, 0, 0);
#pragma unroll
    for (int kc = 0; kc < 4; ++kc)  a1 = MFMA16(af[kc + 4],  bfrag[kc + 4],  a1, 0, 0, 0);
#pragma unroll
    for (int kc = 0; kc < 4; ++kc)  a2 = MFMA16(af[kc + 8],  bfrag[kc + 8],  a2, 0, 0, 0);
#pragma unroll
    for (int kc = 0; kc < 4; ++kc)  a3 = MFMA16(af[kc + 12], bfrag[kc + 12], a3, 0, 0, 0);

    unsigned short* hn = ring + (st & (RING - 1u)) * 8192u;
    unsigned short h16[4];
#pragma unroll
    for (int j = 0; j < 4; ++j) {
      unsigned m = (lid >> 4) * 4u + j;
      float s = uv[j] + (a0[j] + a1[j]) + (a2[j] + a3[j]);
      float e2 = __expf(2.f * s);
      float h = 1.f - 2.f / (e2 + 1.f);       // tanh(s)
      h16[j] = f2bf(h);
      hn[m * 512u + col] = h16[j];
    }
    // history stores issued now; vmcnt(4) below lets them ride behind
#pragma unroll
    for (int j = 0; j < 4; ++j) {
      unsigned m = (lid >> 4) * 4u + j;
      Hs[(m * (unsigned)LSEQ + (st - 1)) * 512u + col] = h16[j];
    }
    // wait only until the 4 ring stores are ack'd in L2 (Hs still in flight)
    asm volatile("s_waitcnt vmcnt(4)" ::: "memory");
    if (lid == 0)
      __hip_atomic_store(&ctrl[wflag], st, __ATOMIC_RELAXED,
                         __HIP_MEMORY_SCOPE_AGENT);
    // next-u prefetch (drains during next spin)
    {
      unsigned tn = (st < LSEQ) ? st : (LSEQ - 1u);
#pragma unroll
      for (int j = 0; j < 4; ++j) {
        unsigned m = (lid >> 4) * 4u + j;
        uv[j] = U[(m * (unsigned)LSEQ + tn) * 512u + col];
      }
    }
  }
}

// ---------------------------------------------------------------------------
// GEMM3 + GLU + residual: Y[r,e]=sum_d Hs[r,d]*Wfb[e,d]+bffn[e]; paired g-tile
// at e+512; out[r,e] = a*sigmoid(g) + x[r,e]  (fp32, overwrites d_out)
// ---------------------------------------------------------------------------
__global__ __launch_bounds__(256) void gemm_ffn_kernel(
    const unsigned short* __restrict__ A, const unsigned short* __restrict__ Bw,
    const float* __restrict__ bffn, const float* __restrict__ x,
    float* __restrict__ out)
{
  __shared__ __align__(16) unsigned char lds[24576]; // A 8KB | Ba 8KB | Bg 8KB
  const unsigned tid = threadIdx.x;
  const unsigned lid = tid & 63u, wid = tid >> 6;
  const unsigned wr = wid >> 1, wc = wid & 1u;
  const unsigned rbase = blockIdx.x * 128u, nbase = blockIdx.y * 128u;

  f32x4 acc_a[4][4] = {}, acc_g[4][4] = {};
  for (int kt = 0; kt < 16; ++kt) {
    __syncthreads();
#pragma unroll
    for (int i = 0; i < 2; ++i) {
      unsigned c = i * 256u + tid;
      const unsigned short* ga = A + (rbase + (c >> 2)) * 512u + kt * 32u + (c & 3u) * 8u;
      __builtin_amdgcn_global_load_lds(AS1(ga), AS3(lds + c * 16u), 16, 0, 0);
      const unsigned short* gb = Bw + (nbase + (c >> 2)) * 512u + kt * 32u + (c & 3u) * 8u;
      __builtin_amdgcn_global_load_lds(AS1(gb), AS3(lds + 8192u + c * 16u), 16, 0, 0);
      const unsigned short* gg = Bw + (512u + nbase + (c >> 2)) * 512u + kt * 32u + (c & 3u) * 8u;
      __builtin_amdgcn_global_load_lds(AS1(gg), AS3(lds + 16384u + c * 16u), 16, 0, 0);
    }
    __syncthreads();
    bf16x8 af[4], ba[4], bg[4];
#pragma unroll
    for (int mi = 0; mi < 4; ++mi)
      af[mi] = *(const bf16x8*)(lds + (wr * 64u + mi * 16u + (lid & 15u)) * 64u + (lid >> 4) * 16u);
#pragma unroll
    for (int ni = 0; ni < 4; ++ni) {
      ba[ni] = *(const bf16x8*)(lds + 8192u  + (wc * 64u + ni * 16u + (lid & 15u)) * 64u + (lid >> 4) * 16u);
      bg[ni] = *(const bf16x8*)(lds + 16384u + (wc * 64u + ni * 16u + (lid & 15u)) * 64u + (lid >> 4) * 16u);
    }
#pragma unroll
    for (int mi = 0; mi < 4; ++mi)
#pragma unroll
      for (int ni = 0; ni < 4; ++ni) {
        acc_a[mi][ni] = MFMA16(af[mi], ba[ni], acc_a[mi][ni], 0, 0, 0);
        acc_g[mi][ni] = MFMA16(af[mi], bg[ni], acc_g[mi][ni], 0, 0, 0);
      }
  }
#pragma unroll
  for (int mi = 0; mi < 4; ++mi)
#pragma unroll
    for (int ni = 0; ni < 4; ++ni) {
      unsigned e = nbase + wc * 64u + ni * 16u + (lid & 15u);
      float bba = bffn[e], bbg = bffn[e + 512u];
#pragma unroll
      for (int j = 0; j < 4; ++j) {
        unsigned r = rbase + wr * 64u + mi * 16u + (lid >> 4) * 4u + j;
        float a  = acc_a[mi][ni][j] + bba;
        float gg = acc_g[mi][ni][j] + bbg;
        float sg = 1.f / (1.f + __expf(-gg));
        out[r * 512u + e] = a * sg + x[r * 512u + e];
      }
    }
}

// ---------------------------------------------------------------------------
extern "C" void kernel_launch(void* const* d_in, const int* in_sizes, int n_in,
                              void* d_out, int out_size, void* d_ws, size_t ws_size,
                              hipStream_t stream) {
  const float* x     = (const float*)d_in[0];
  const float* gamma = (const float*)d_in[1];
  const float* beta  = (const float*)d_in[2];
  const float* mean  = (const float*)d_in[3];
  const float* var   = (const float*)d_in[4];
  const float* Wx    = (const float*)d_in[5];
  const float* Wh    = (const float*)d_in[6];
  const float* brnn  = (const float*)d_in[7];
  const float* Wffn  = (const float*)d_in[8];
  const float* bffn  = (const float*)d_in[9];
  float* out = (float*)d_out;

  // workspace layout
  unsigned char* ws = (unsigned char*)d_ws;
  unsigned short* Hs   = (unsigned short*)(ws);                     // 32 MB
  unsigned short* Xbf  = (unsigned short*)(ws + (size_t)33554432);  // 32 MB
  unsigned short* Wxp  = (unsigned short*)(ws + (size_t)67108864);  // 512 KB
  unsigned short* Wfb  = (unsigned short*)(ws + (size_t)67633152);  // 1 MB
  float*          bpr  = (float*)        (ws + (size_t)68681728);   // 2 KB
  // ring (1 MB) + ctrl (4 KB) ALIAS the Xbf region: Xbf is dead after
  // gemm_u, and the memsets below are stream-ordered after gemm_u.
  unsigned short* ring = (unsigned short*)(ws + (size_t)33554432);
  unsigned int*   ctrl = (unsigned int*)  (ws + (size_t)33554432 + 1048576);

  // U (input projection, fp32, 64MB) lives in d_out; overwritten by FFN epilogue
  float* U = out;

  prep_kernel<<<1536, 256, 0, stream>>>(Wx, gamma, beta, mean, var, brnn, Wffn,
                                        Wxp, Wfb, bpr);
  convx_kernel<<<2048, 256, 0, stream>>>(x, Xbf);
  gemm_u_kernel<<<dim3(256, 4), 256, 0, stream>>>(Xbf, Wxp, bpr, U);
  hipMemsetAsync(ring, 0, 16384, stream);  // h0 = 0 (ring slot 0)
  hipMemsetAsync(ctrl, 0, 4096, stream);   // flags[32], claim[8], chosen = 0
  rnn_rec_kernel<<<256, 256, 0, stream>>>(Wh, U, Hs, ring, ctrl);
  gemm_ffn_kernel<<<dim3(256, 4), 256, 0, stream>>>(Hs, Wfb, bffn, x, out);
}

// Round 6
// 6652.592 us; speedup vs baseline: 1.0209x; 1.0209x over previous
//
#include <hip/hip_runtime.h>
#include <math.h>

// Problem constants
#define DD   512
#define LSEQ 2048
#define NBAT 16
#define RTOT (NBAT * LSEQ)   // 32768 rows
#define RING 64              // h ring depth (1 MB; defeats consumer-L1 staleness)

typedef __attribute__((ext_vector_type(8))) short bf16x8;
typedef __attribute__((ext_vector_type(4))) float f32x4;

#define AS1(p) ((const __attribute__((address_space(1))) void*)(p))
#define AS3(p) ((__attribute__((address_space(3))) void*)(p))
#define MFMA16 __builtin_amdgcn_mfma_f32_16x16x32_bf16

__device__ __forceinline__ unsigned short f2bf(float f) {
  unsigned u = __builtin_bit_cast(unsigned, f);
  u += 0x7fffu + ((u >> 16) & 1u);
  return (unsigned short)(u >> 16);
}

// ---------------------------------------------------------------------------
// prep: fold BN into Wx (Wx' = Wx*diag(inv), b' = Wx(beta-mean*iv)+b_rnn),
// convert Wffn to bf16.  blocks 0..511: Wx' row + b' ; blocks 512..1535: Wffn.
// ---------------------------------------------------------------------------
__global__ __launch_bounds__(256) void prep_kernel(
    const float* __restrict__ Wx, const float* __restrict__ gamma,
    const float* __restrict__ beta, const float* __restrict__ mean,
    const float* __restrict__ var, const float* __restrict__ brnn,
    const float* __restrict__ Wffn,
    unsigned short* __restrict__ Wxp, unsigned short* __restrict__ Wfb,
    float* __restrict__ bprime)
{
  const unsigned tid = threadIdx.x, bx = blockIdx.x;
  if (bx < 512) {
    __shared__ float red[256];
    float partial = 0.f;
#pragma unroll
    for (int i = 0; i < 2; ++i) {
      unsigned d = i * 256u + tid;
      float iv = gamma[d] * rsqrtf(var[d] + 1e-5f);
      float w  = Wx[bx * 512u + d];
      Wxp[bx * 512u + d] = (unsigned short)f2bf(w * iv);
      partial += w * (beta[d] - mean[d] * iv);
    }
    red[tid] = partial; __syncthreads();
    for (unsigned s = 128; s > 0; s >>= 1) {
      if (tid < s) red[tid] += red[tid + s];
      __syncthreads();
    }
    if (tid == 0) bprime[bx] = red[0] + brnn[bx];
  } else {
    unsigned row = bx - 512;
#pragma unroll
    for (int i = 0; i < 2; ++i) {
      unsigned d = i * 256u + tid;
      Wfb[row * 512u + d] = (unsigned short)f2bf(Wffn[row * 512u + d]);
    }
  }
}

// ---------------------------------------------------------------------------
// convert x (fp32) -> bf16, row-major (RTOT, D)
// ---------------------------------------------------------------------------
__global__ __launch_bounds__(256) void convx_kernel(
    const float* __restrict__ x, unsigned short* __restrict__ Xbf)
{
  const unsigned total4 = RTOT * DD / 4;
  unsigned i = blockIdx.x * 256u + threadIdx.x;
  const unsigned stride = gridDim.x * 256u;
  const float4* __restrict__ x4 = (const float4*)x;
  for (; i < total4; i += stride) {
    float4 v = x4[i];
    unsigned short o0 = f2bf(v.x), o1 = f2bf(v.y), o2 = f2bf(v.z), o3 = f2bf(v.w);
    unsigned long long pack = (unsigned long long)o0 |
                              ((unsigned long long)o1 << 16) |
                              ((unsigned long long)o2 << 32) |
                              ((unsigned long long)o3 << 48);
    *(unsigned long long*)(Xbf + i * 4u) = pack;
  }
}

// ---------------------------------------------------------------------------
// GEMM1: U[r,e] = sum_d Xbf[r,d]*Wxp[e,d] + b'[e]   (fp32 out into d_out)
// ---------------------------------------------------------------------------
__global__ __launch_bounds__(256) void gemm_u_kernel(
    const unsigned short* __restrict__ A, const unsigned short* __restrict__ Bw,
    const float* __restrict__ bias, float* __restrict__ U)
{
  __shared__ __align__(16) unsigned char lds[16384]; // A 8KB | B 8KB
  const unsigned tid = threadIdx.x;
  const unsigned lid = tid & 63u, wid = tid >> 6;
  const unsigned wr = wid >> 1, wc = wid & 1u;
  const unsigned rbase = blockIdx.x * 128u, nbase = blockIdx.y * 128u;

  f32x4 acc[4][4] = {};
  for (int kt = 0; kt < 16; ++kt) {
    __syncthreads();
#pragma unroll
    for (int i = 0; i < 2; ++i) {
      unsigned c = i * 256u + tid;
      const unsigned short* g = A + (rbase + (c >> 2)) * 512u + kt * 32u + (c & 3u) * 8u;
      __builtin_amdgcn_global_load_lds(AS1(g), AS3(lds + c * 16u), 16, 0, 0);
    }
#pragma unroll
    for (int i = 0; i < 2; ++i) {
      unsigned c = i * 256u + tid;
      const unsigned short* g = Bw + (nbase + (c >> 2)) * 512u + kt * 32u + (c & 3u) * 8u;
      __builtin_amdgcn_global_load_lds(AS1(g), AS3(lds + 8192u + c * 16u), 16, 0, 0);
    }
    __syncthreads();
    bf16x8 af[4], bfr[4];
#pragma unroll
    for (int mi = 0; mi < 4; ++mi)
      af[mi] = *(const bf16x8*)(lds + (wr * 64u + mi * 16u + (lid & 15u)) * 64u + (lid >> 4) * 16u);
#pragma unroll
    for (int ni = 0; ni < 4; ++ni)
      bfr[ni] = *(const bf16x8*)(lds + 8192u + (wc * 64u + ni * 16u + (lid & 15u)) * 64u + (lid >> 4) * 16u);
#pragma unroll
    for (int mi = 0; mi < 4; ++mi)
#pragma unroll
      for (int ni = 0; ni < 4; ++ni)
        acc[mi][ni] = MFMA16(af[mi], bfr[ni], acc[mi][ni], 0, 0, 0);
  }
#pragma unroll
  for (int mi = 0; mi < 4; ++mi)
#pragma unroll
    for (int ni = 0; ni < 4; ++ni) {
      unsigned e = nbase + wc * 64u + ni * 16u + (lid & 15u);
      float bb = bias[e];
#pragma unroll
      for (int j = 0; j < 4; ++j) {
        unsigned r = rbase + wr * 64u + mi * 16u + (lid >> 4) * 4u + j;
        U[r * 512u + e] = acc[mi][ni][j] + bb;
      }
    }
}

// ---------------------------------------------------------------------------
// Recurrence: 2 WGs x 4 waves (1 wave/SIMD), same XCD via claim. Wave owns
// N=64 cols with full-K Wh stationary in 256 VGPRs. Own K-half of h in LDS;
// remote K-half via 64-slot L2 ring. Sync: 8 per-wave flags, inline-asm
// global_atomic_add with NO sc1 (executes at XCD-shared L2; never L1-stale).
// ---------------------------------------------------------------------------
__global__ __launch_bounds__(256, 1) void rnn_rec_kernel(
    const float* __restrict__ Wh, const float* __restrict__ U,
    unsigned short* __restrict__ Hs, unsigned short* __restrict__ ring,
    unsigned int* __restrict__ ctrl)
{
  __shared__ unsigned s_g;
  __shared__ unsigned short hl[16][264];   // own K-half, +8 pad (2-way banks)

  if (threadIdx.x == 0) {
    unsigned xcc;
    asm volatile("s_getreg_b32 %0, hwreg(HW_REG_XCC_ID)" : "=s"(xcc));
    xcc &= 7u;
    unsigned mygrp = 0xffffffffu;
    unsigned slot = __hip_atomic_fetch_add(&ctrl[512 + xcc], 1u, __ATOMIC_RELAXED,
                                           __HIP_MEMORY_SCOPE_AGENT);
    if (slot < 2u) {
      if (slot == 1u) {
        unsigned expected = 0u;
        __hip_atomic_compare_exchange_strong(&ctrl[520], &expected, xcc + 1u,
            __ATOMIC_RELEASE, __ATOMIC_RELAXED, __HIP_MEMORY_SCOPE_AGENT);
      }
      unsigned ch, gu = 0;
      do {
        ch = __hip_atomic_load(&ctrl[520], __ATOMIC_ACQUIRE, __HIP_MEMORY_SCOPE_AGENT);
      } while (ch == 0u && ++gu < 200000000u);
      if (ch == xcc + 1u) mygrp = slot;
    }
    s_g = mygrp;
  }
  __syncthreads();
  const unsigned g = s_g;
  if (g == 0xffffffffu) return;

  const unsigned tid = threadIdx.x, lid = tid & 63u, w = tid >> 6;
  const unsigned m0   = (lid >> 4);
  const unsigned nloc = w * 64u;
  const unsigned nabs = g * 256u + nloc;

  for (unsigned i = tid; i < 16u * 264u; i += 256u) ((unsigned short*)hl)[i] = 0;

  // stationary Wh B-fragments (own-half chunks bo, remote-half chunks br)
  bf16x8 bo[8][4], br[8][4];
#pragma unroll
  for (int i = 0; i < 8; ++i)
#pragma unroll
    for (int nt = 0; nt < 4; ++nt) {
      unsigned n = nabs + nt * 16u + (lid & 15u);
      unsigned ko = (g * 8u + i) * 32u + m0 * 8u;
      unsigned kr = ((1u ^ g) * 8u + i) * 32u + m0 * 8u;
      bf16x8 t1, t2;
#pragma unroll
      for (int j = 0; j < 8; ++j) {
        t1[j] = (short)f2bf(Wh[n * 512u + ko + j]);
        t2[j] = (short)f2bf(Wh[n * 512u + kr + j]);
      }
      bo[i][nt] = t1; br[i][nt] = t2;
    }

  // prefetch u for step 1 (t=0)
  f32x4 uv[4];
#pragma unroll
  for (int nt = 0; nt < 4; ++nt)
#pragma unroll
    for (int j = 0; j < 4; ++j) {
      unsigned m = m0 * 4u + j;
      unsigned n = nabs + nt * 16u + (lid & 15u);
      uv[nt][j] = U[(m * (unsigned)LSEQ + 0u) * 512u + n];
    }

  unsigned int* myflag = ctrl + (g * 4u + w) * 16u;
  unsigned int* rf     = ctrl + ((1u ^ g) * 4u + (lid & 3u)) * 16u;
  const unsigned zero = 0u, one = 1u;
  const unsigned ringoff = (lid & 15u) * 512u + m0 * 8u;
  const unsigned ldsrow  = (lid & 15u);

  __syncthreads();

  unsigned budget = 5000000u;
  for (unsigned st = 1; st <= LSEQ; ++st) {
    const unsigned tgt = st - 1;

    // poll remote wave-flags (lanes 0-3; L2-local RMW, returns old)
    {
      unsigned f = 0xffffffffu;
      if (lid < 4u)
        asm volatile("global_atomic_add %0, %1, %2, off sc0\n\ts_waitcnt vmcnt(0)"
                     : "=v"(f) : "v"(rf), "v"(zero) : "memory");
      while (__ballot(f >= tgt) != ~0ull) {
        if (--budget == 0u) break;
        if (lid < 4u)
          asm volatile("global_atomic_add %0, %1, %2, off sc0\n\ts_waitcnt vmcnt(0)"
                       : "=v"(f) : "v"(rf), "v"(zero) : "memory");
      }
    }
    __builtin_amdgcn_sched_barrier(0);

    f32x4 acc[4];
#pragma unroll
    for (int nt = 0; nt < 4; ++nt) acc[nt] = uv[nt];

    // own K-half from LDS
    bf16x8 ao[8];
#pragma unroll
    for (int i = 0; i < 8; ++i)
      ao[i] = *(const bf16x8*)&hl[ldsrow][i * 32u + m0 * 8u];
#pragma unroll
    for (int i = 0; i < 8; ++i)
#pragma unroll
      for (int nt = 0; nt < 4; ++nt)
        acc[nt] = MFMA16(ao[i], bo[i][nt], acc[nt], 0, 0, 0);

    // remote K-half from ring
    const unsigned short* rb = ring + ((st - 1u) & (RING - 1u)) * 8192u
                             + (1u ^ g) * 256u + ringoff;
    bf16x8 ar[8];
#pragma unroll
    for (int i = 0; i < 8; ++i)
      ar[i] = *(const bf16x8*)(rb + i * 32u);
#pragma unroll
    for (int i = 0; i < 8; ++i)
#pragma unroll
      for (int nt = 0; nt < 4; ++nt)
        acc[nt] = MFMA16(ar[i], br[i][nt], acc[nt], 0, 0, 0);

    // tanh -> h_t; write own LDS + ring slot
    unsigned short* wslot = ring + (st & (RING - 1u)) * 8192u;
    unsigned short h16[4][4];
#pragma unroll
    for (int nt = 0; nt < 4; ++nt)
#pragma unroll
      for (int j = 0; j < 4; ++j) {
        float s = acc[nt][j];
        float e2 = __expf(2.f * s);
        float h = 1.f - 2.f / (e2 + 1.f);
        h16[nt][j] = f2bf(h);
        unsigned m = m0 * 4u + j;
        hl[m][nloc + nt * 16u + (lid & 15u)] = h16[nt][j];
        wslot[m * 512u + nabs + nt * 16u + (lid & 15u)] = h16[nt][j];
      }

    asm volatile("s_waitcnt vmcnt(0)" ::: "memory");  // ring stores in L2
    if (lid == 0)
      asm volatile("global_atomic_add %0, %1, off"
                   :: "v"(myflag), "v"(one) : "memory");
    __syncthreads();

    // off-critical-path: history store + next-u prefetch
#pragma unroll
    for (int nt = 0; nt < 4; ++nt)
#pragma unroll
      for (int j = 0; j < 4; ++j) {
        unsigned m = m0 * 4u + j;
        unsigned n = nabs + nt * 16u + (lid & 15u);
        Hs[(m * (unsigned)LSEQ + (st - 1)) * 512u + n] = h16[nt][j];
      }
    {
      unsigned tn = (st < LSEQ) ? st : (LSEQ - 1u);
#pragma unroll
      for (int nt = 0; nt < 4; ++nt)
#pragma unroll
        for (int j = 0; j < 4; ++j) {
          unsigned m = m0 * 4u + j;
          unsigned n = nabs + nt * 16u + (lid & 15u);
          uv[nt][j] = U[(m * (unsigned)LSEQ + tn) * 512u + n];
        }
    }
  }
}

// ---------------------------------------------------------------------------
// GEMM3 + GLU + residual (unchanged)
// ---------------------------------------------------------------------------
__global__ __launch_bounds__(256) void gemm_ffn_kernel(
    const unsigned short* __restrict__ A, const unsigned short* __restrict__ Bw,
    const float* __restrict__ bffn, const float* __restrict__ x,
    float* __restrict__ out)
{
  __shared__ __align__(16) unsigned char lds[24576];
  const unsigned tid = threadIdx.x;
  const unsigned lid = tid & 63u, wid = tid >> 6;
  const unsigned wr = wid >> 1, wc = wid & 1u;
  const unsigned rbase = blockIdx.x * 128u, nbase = blockIdx.y * 128u;

  f32x4 acc_a[4][4] = {}, acc_g[4][4] = {};
  for (int kt = 0; kt < 16; ++kt) {
    __syncthreads();
#pragma unroll
    for (int i = 0; i < 2; ++i) {
      unsigned c = i * 256u + tid;
      const unsigned short* ga = A + (rbase + (c >> 2)) * 512u + kt * 32u + (c & 3u) * 8u;
      __builtin_amdgcn_global_load_lds(AS1(ga), AS3(lds + c * 16u), 16, 0, 0);
      const unsigned short* gb = Bw + (nbase + (c >> 2)) * 512u + kt * 32u + (c & 3u) * 8u;
      __builtin_amdgcn_global_load_lds(AS1(gb), AS3(lds + 8192u + c * 16u), 16, 0, 0);
      const unsigned short* gg = Bw + (512u + nbase + (c >> 2)) * 512u + kt * 32u + (c & 3u) * 8u;
      __builtin_amdgcn_global_load_lds(AS1(gg), AS3(lds + 16384u + c * 16u), 16, 0, 0);
    }
    __syncthreads();
    bf16x8 af[4], ba[4], bg[4];
#pragma unroll
    for (int mi = 0; mi < 4; ++mi)
      af[mi] = *(const bf16x8*)(lds + (wr * 64u + mi * 16u + (lid & 15u)) * 64u + (lid >> 4) * 16u);
#pragma unroll
    for (int ni = 0; ni < 4; ++ni) {
      ba[ni] = *(const bf16x8*)(lds + 8192u  + (wc * 64u + ni * 16u + (lid & 15u)) * 64u + (lid >> 4) * 16u);
      bg[ni] = *(const bf16x8*)(lds + 16384u + (wc * 64u + ni * 16u + (lid & 15u)) * 64u + (lid >> 4) * 16u);
    }
#pragma unroll
    for (int mi = 0; mi < 4; ++mi)
#pragma unroll
      for (int ni = 0; ni < 4; ++ni) {
        acc_a[mi][ni] = MFMA16(af[mi], ba[ni], acc_a[mi][ni], 0, 0, 0);
        acc_g[mi][ni] = MFMA16(af[mi], bg[ni], acc_g[mi][ni], 0, 0, 0);
      }
  }
#pragma unroll
  for (int mi = 0; mi < 4; ++mi)
#pragma unroll
    for (int ni = 0; ni < 4; ++ni) {
      unsigned e = nbase + wc * 64u + ni * 16u + (lid & 15u);
      float bba = bffn[e], bbg = bffn[e + 512u];
#pragma unroll
      for (int j = 0; j < 4; ++j) {
        unsigned r = rbase + wr * 64u + mi * 16u + (lid >> 4) * 4u + j;
        float a  = acc_a[mi][ni][j] + bba;
        float gg = acc_g[mi][ni][j] + bbg;
        float sg = 1.f / (1.f + __expf(-gg));
        out[r * 512u + e] = a * sg + x[r * 512u + e];
      }
    }
}

// ---------------------------------------------------------------------------
extern "C" void kernel_launch(void* const* d_in, const int* in_sizes, int n_in,
                              void* d_out, int out_size, void* d_ws, size_t ws_size,
                              hipStream_t stream) {
  const float* x     = (const float*)d_in[0];
  const float* gamma = (const float*)d_in[1];
  const float* beta  = (const float*)d_in[2];
  const float* mean  = (const float*)d_in[3];
  const float* var   = (const float*)d_in[4];
  const float* Wx    = (const float*)d_in[5];
  const float* Wh    = (const float*)d_in[6];
  const float* brnn  = (const float*)d_in[7];
  const float* Wffn  = (const float*)d_in[8];
  const float* bffn  = (const float*)d_in[9];
  float* out = (float*)d_out;

  unsigned char* ws = (unsigned char*)d_ws;
  unsigned short* Hs   = (unsigned short*)(ws);                     // 32 MB
  unsigned short* Xbf  = (unsigned short*)(ws + (size_t)33554432);  // 32 MB
  unsigned short* Wxp  = (unsigned short*)(ws + (size_t)67108864);  // 512 KB
  unsigned short* Wfb  = (unsigned short*)(ws + (size_t)67633152);  // 1 MB
  float*          bpr  = (float*)        (ws + (size_t)68681728);   // 2 KB
  unsigned short* ring = (unsigned short*)(ws + (size_t)33554432);  // alias Xbf
  unsigned int*   ctrl = (unsigned int*)  (ws + (size_t)33554432 + 1048576);

  float* U = out;

  prep_kernel<<<1536, 256, 0, stream>>>(Wx, gamma, beta, mean, var, brnn, Wffn,
                                        Wxp, Wfb, bpr);
  convx_kernel<<<2048, 256, 0, stream>>>(x, Xbf);
  gemm_u_kernel<<<dim3(256, 4), 256, 0, stream>>>(Xbf, Wxp, bpr, U);
  hipMemsetAsync(ring, 0, 16384, stream);  // h0 = 0 (ring slot 0)
  hipMemsetAsync(ctrl, 0, 4096, stream);   // flags[8], claim[8], chosen = 0
  rnn_rec_kernel<<<256, 256, 0, stream>>>(Wh, U, Hs, ring, ctrl);
  gemm_ffn_kernel<<<dim3(256, 4), 256, 0, stream>>>(Hs, Wfb, bffn, x, out);
}